// Round 5
// baseline (295.868 us; speedup 1.0000x reference)
//
#include <hip/hip_runtime.h>
#include <math.h>

// Problem constants
#define NS      32768           // N_SAMPLES
#define M       16384           // NS/2, packed complex FFT length = 4^7
#define NEV     16
#define NB      64
#define T2      1024            // threads for FFT kernels (16 waves)

// LDS pad: break power-of-4 strides (incl. 1024/4096 from digit-reversal scatter)
__device__ __forceinline__ int ldsIdx(int i) { return i + (i >> 5) + (i >> 10); }
#define LDS_ELEMS (M + M / 32 + M / 1024)   // 16912 float2 = 135296 B < 160 KB

__device__ __forceinline__ float2 cmul(float2 a, float2 b) {
    return make_float2(a.x * b.x - a.y * b.y, a.x * b.y + a.y * b.x);
}

// reverse 7 base-4 digits (14 bits). Pure BIT permutation: rev(x|y)=rev(x)|rev(y)
// for disjoint bit support.
__device__ __forceinline__ int rev4_14(int i) {
    int r = 0;
#pragma unroll
    for (int d = 0; d < 7; ++d) { r = (r << 2) | (i & 3); i >>= 2; }
    return r;
}

// e^{-i*2*pi*k*s/NS}, s = si + sf (integer + fraction), exact integer mod
__device__ __forceinline__ float2 shift_phase(int k, int si, float sf) {
    unsigned ksi = ((unsigned)k * (unsigned)si) & (unsigned)(NS - 1);
    float total = (float)ksi + (float)k * sf;
    float f = total * (1.0f / (float)NS);
    f -= floorf(f);
    float ang = -6.28318530717958647692f * f;
    float sv, cv;
    __sincosf(ang, &sv, &cv);
    return make_float2(cv, sv);
}

// e^{-2*pi*i*k/NS}
__device__ __forceinline__ float2 wNS(int k) {
    float ang = (float)k * (-6.28318530717958647692f / (float)NS);
    float sv, cv;
    __sincosf(ang, &sv, &cv);
    return make_float2(cv, sv);
}

// cos/sin(2*pi*n/16), n = 0..3
__device__ __constant__ float R16C[4] = {1.0f, 0.92387953251128675613f,
                                         0.70710678118654752440f, 0.38268343236508977173f};
__device__ __constant__ float R16S[4] = {0.0f, 0.38268343236508977173f,
                                         0.70710678118654752440f, 0.92387953251128675613f};

// cos/sin(2*pi*t/32), t = 0..15  (rotation per +1024 step of k: e^{-2pi*i*k/NS})
__device__ __constant__ float C32[16] = {
    1.0f, 0.98078528040323044913f, 0.92387953251128675613f, 0.83146961230254523708f,
    0.70710678118654752440f, 0.55557023301960222474f, 0.38268343236508977173f,
    0.19509032201612826785f, 0.0f, -0.19509032201612826785f, -0.38268343236508977173f,
    -0.55557023301960222474f, -0.70710678118654752440f, -0.83146961230254523708f,
    -0.92387953251128675613f, -0.98078528040323044913f};
__device__ __constant__ float S32[16] = {
    0.0f, 0.19509032201612826785f, 0.38268343236508977173f, 0.55557023301960222474f,
    0.70710678118654752440f, 0.83146961230254523708f, 0.92387953251128675613f,
    0.98078528040323044913f, 1.0f, 0.98078528040323044913f, 0.92387953251128675613f,
    0.83146961230254523708f, 0.70710678118654752440f, 0.55557023301960222474f,
    0.38268343236508977173f, 0.19509032201612826785f};

// radix-4 butterfly, no twiddle, in place
template <int SIGN>
__device__ __forceinline__ void btf4(float2* a) {
    float2 a0 = a[0], a1 = a[1], a2 = a[2], a3 = a[3];
    float2 u0 = make_float2(a0.x + a2.x, a0.y + a2.y);
    float2 u1 = make_float2(a0.x - a2.x, a0.y - a2.y);
    float2 u2 = make_float2(a1.x + a3.x, a1.y + a3.y);
    float2 u3 = make_float2(a1.x - a3.x, a1.y - a3.y);
    a[0] = make_float2(u0.x + u2.x, u0.y + u2.y);
    a[2] = make_float2(u0.x - u2.x, u0.y - u2.y);
    if (SIGN < 0) {
        a[1] = make_float2(u1.x + u3.y, u1.y - u3.x);  // u1 - i*u3
        a[3] = make_float2(u1.x - u3.y, u1.y + u3.x);  // u1 + i*u3
    } else {
        a[1] = make_float2(u1.x - u3.y, u1.y + u3.x);
        a[3] = make_float2(u1.x + u3.y, u1.y - u3.x);
    }
}

// Fused: coalesced float4 load of a natural-order row -> radix-4 STAGE 0 in
// registers -> digit-reversed scatter into LDS.
// rev(2i) = rev(2*tid) | rev(it*2048), rev(it*2048) in {0,8,1,9,2,10,3,11},
// rev(2i+1) = rev(2i) | 4096.
// SPLIT INTO TWO 4-LOAD HALVES (even its -> R+{0..3}, odd its -> R+8+{0..3})
// to keep peak live registers inside the 64-VGPR budget — the 8-load version
// spilled 1 float2/thread to scratch (round-4 counters: WRITE_SIZE +8.25 MB).
template <int SIGN>
__device__ __forceinline__ void load_stage0_scatter(const float4* __restrict__ src,
                                                    float2* lds, int tid) {
    const int R = rev4_14(2 * tid);
    {   // half A: it = 0,2,4,6 -> rev offsets l = 0..3
        float2 g0[4], g1[4];
#pragma unroll
        for (int l = 0; l < 4; ++l) {
            float4 v = src[tid + ((2 * l) << 10)];
            g0[l] = make_float2(v.x, v.y);
            g1[l] = make_float2(v.z, v.w);
        }
        btf4<SIGN>(g0); btf4<SIGN>(g1);
#pragma unroll
        for (int l = 0; l < 4; ++l) {
            lds[ldsIdx(R + l)]        = g0[l];
            lds[ldsIdx(R + 4096 + l)] = g1[l];
        }
    }
    {   // half B: it = 1,3,5,7 -> rev offsets 8 + l
        float2 g2[4], g3[4];
#pragma unroll
        for (int l = 0; l < 4; ++l) {
            float4 v = src[tid + ((2 * l + 1) << 10)];
            g2[l] = make_float2(v.x, v.y);
            g3[l] = make_float2(v.z, v.w);
        }
        btf4<SIGN>(g2); btf4<SIGN>(g3);
#pragma unroll
        for (int l = 0; l < 4; ++l) {
            lds[ldsIdx(R + 8 + l)]        = g2[l];
            lds[ldsIdx(R + 8 + 4096 + l)] = g3[l];
        }
    }
}

// Fused stage pairs (1,2),(3,4),(5,6) (stage 0 done in registers at load).
// ONE sincos per pair: ww = e^{TP*j/(16q)}; stage-t twiddle = ww^4.
template <int SIGN>
__device__ void fft_pairs(float2* lds, int tid) {
    const float TP = (SIGN < 0) ? -6.28318530717958647692f
                                :  6.28318530717958647692f;
#pragma unroll
    for (int tp = 0; tp < 3; ++tp) {         // stage pairs (1,2),(3,4),(5,6)
        const int t = 2 * tp + 1;
        const int q = 1 << (2 * t);          // 4, 64, 1024
        const int j = tid & (q - 1);
        const int base = ((tid >> (2 * t)) << (2 * t + 4)) + j;
        float2 x[16];
#pragma unroll
        for (int l = 0; l < 16; ++l) x[l] = lds[ldsIdx(base + l * q)];

        float sv, cv;
        __sincosf(TP * (float)j / (float)(16 * q), &sv, &cv);
        float2 ww = make_float2(cv, sv);     // stage t+1 base twiddle
        float2 s2 = cmul(ww, ww);
        float2 w1 = cmul(s2, s2);            // ww^4 = e^{TP*j/(4q)}
        float2 w2 = cmul(w1, w1);
        float2 w3 = cmul(w2, w1);

        // ---- stage t: butterflies (4m..4m+3), twiddle w1^n ----
#pragma unroll
        for (int m = 0; m < 4; ++m) {
            float2 a0 = x[4 * m], a1 = x[4 * m + 1], a2 = x[4 * m + 2], a3 = x[4 * m + 3];
            a1 = cmul(a1, w1); a2 = cmul(a2, w2); a3 = cmul(a3, w3);
            float2 u0 = make_float2(a0.x + a2.x, a0.y + a2.y);
            float2 u1 = make_float2(a0.x - a2.x, a0.y - a2.y);
            float2 u2 = make_float2(a1.x + a3.x, a1.y + a3.y);
            float2 u3 = make_float2(a1.x - a3.x, a1.y - a3.y);
            x[4 * m]     = make_float2(u0.x + u2.x, u0.y + u2.y);
            x[4 * m + 2] = make_float2(u0.x - u2.x, u0.y - u2.y);
            if (SIGN < 0) {
                x[4 * m + 1] = make_float2(u1.x + u3.y, u1.y - u3.x);
                x[4 * m + 3] = make_float2(u1.x - u3.y, u1.y + u3.x);
            } else {
                x[4 * m + 1] = make_float2(u1.x - u3.y, u1.y + u3.x);
                x[4 * m + 3] = make_float2(u1.x + u3.y, u1.y - u3.x);
            }
        }

        // ---- stage t+1: butterflies (n, n+4, n+8, n+12), twiddle (ww*r16^n)^m ----
#pragma unroll
        for (int n = 0; n < 4; ++n) {
            float2 a0 = x[n], a1 = x[n + 4], a2 = x[n + 8], a3 = x[n + 12];
            {
                float2 r = make_float2(R16C[n], (SIGN < 0) ? -R16S[n] : R16S[n]);
                float2 wp = (n > 0) ? cmul(ww, r) : ww;
                float2 wp2 = cmul(wp, wp);
                float2 wp3 = cmul(wp2, wp);
                a1 = cmul(a1, wp);
                a2 = cmul(a2, wp2);
                a3 = cmul(a3, wp3);
            }
            float2 u0 = make_float2(a0.x + a2.x, a0.y + a2.y);
            float2 u1 = make_float2(a0.x - a2.x, a0.y - a2.y);
            float2 u2 = make_float2(a1.x + a3.x, a1.y + a3.y);
            float2 u3 = make_float2(a1.x - a3.x, a1.y - a3.y);
            x[n]      = make_float2(u0.x + u2.x, u0.y + u2.y);
            x[n + 8]  = make_float2(u0.x - u2.x, u0.y - u2.y);
            if (SIGN < 0) {
                x[n + 4]  = make_float2(u1.x + u3.y, u1.y - u3.x);
                x[n + 12] = make_float2(u1.x - u3.y, u1.y + u3.x);
            } else {
                x[n + 4]  = make_float2(u1.x - u3.y, u1.y + u3.x);
                x[n + 12] = make_float2(u1.x + u3.y, u1.y - u3.x);
            }
        }
#pragma unroll
        for (int l = 0; l < 16; ++l) lds[ldsIdx(base + l * q)] = x[l];
        __syncthreads();
    }
}

// z-pair: given per-stem A[k] (=a), A[M-k] (=bb), w = e^{-2pi*i*k/NS},
// produce packed-inverse inputs Z'[k] (=z1), Z'[M-k] (=z2). LINEAR in (a,bb),
// so per-stem zpair then summing over events == summing then zpair.
__device__ __forceinline__ void zpair(float2 a, float2 bb, float2 w,
                                      float2* z1, float2* z2) {
    float2 E1 = make_float2(0.5f * (a.x + bb.x), 0.5f * (a.y - bb.y));
    float2 D1 = make_float2(0.5f * (a.x - bb.x), 0.5f * (a.y + bb.y));
    float2 O1 = cmul(make_float2(w.x, -w.y), D1);
    *z1 = make_float2(E1.x - O1.y, E1.y + O1.x);          // E1 + i*O1
    float2 D2 = make_float2(-D1.x, D1.y);                  // -conj(D1)
    float2 O2p = cmul(w, D2);                              // O2 = -O2p
    *z2 = make_float2(E1.x + O2p.y, -E1.y - O2p.x);        // conj(E1) + i*O2
}

// Kernel A: one block per (b,e). Wave 0 computes the shift (pos folded in).
// Load+stage0+scatter -> stage pairs -> unpack HALF-SPECTRUM (k=0..M/2):
// from (Zk, Zr) get BOTH X[k]=E+wo and X[M-k]=conj(E-wo); phase both
// (ph(M-k) = e^{-i*pi*s} * conj(ph(k)), exact si-parity); zpair -> write the
// per-stem PACKED inverse-FFT input Z'_e row in natural order to zout
// (workspace when available — avoids clobbering the stems input and the
// harness's 128 MB re-poison copy; falls back to in-place).
__global__ __launch_bounds__(T2, 4) void fft_phase_kernel(const float* __restrict__ stems,
                                                          float* __restrict__ zout,
                                                          const float* __restrict__ tl,
                                                          const float* __restrict__ W,
                                                          const float* __restrict__ bp) {
    __shared__ float2 lds[LDS_ELEMS];
    __shared__ float sh_shift;
    const int tid = threadIdx.x;
    const int row = blockIdx.x;
    const float* rowp = stems + (size_t)row * NS;

    if (tid < 64) {   // wave 0: pos = sigmoid(dot(tl,W)+b) * NS
        const float* trow = tl + (size_t)row * 128;
        float p = trow[tid] * W[tid] + trow[tid + 64] * W[tid + 64];
#pragma unroll
        for (int off = 32; off > 0; off >>= 1) p += __shfl_down(p, off);
        if (tid == 0) {
            float x = p + bp[0];
            sh_shift = (1.0f / (1.0f + expf(-x))) * (float)NS;
        }
    }

    load_stage0_scatter<-1>((const float4*)rowp, lds, tid);
    __syncthreads();
    fft_pairs<-1>(lds, tid);

    const float s = sh_shift;
    const int si = (int)floorf(s);
    const float sf = s - (float)si;
    float2* spec = (float2*)(zout + (size_t)row * NS);

    // phM = e^{-i*pi*s} exactly: (-1)^si * e^{-i*pi*sf}
    float msv, mcv;
    __sincosf(-3.14159265358979323846f * sf, &msv, &mcv);
    float2 phM = make_float2(mcv, msv);
    if (si & 1) { phM.x = -phM.x; phM.y = -phM.y; }

    const float2 ph0 = shift_phase(tid, si, sf);   // e^{-i*2pi*tid*s/NS}
    const float2 w0  = wNS(tid);                   // e^{-i*2pi*tid/NS}
    const float2 q1  = shift_phase(1024, si, sf);  // e^{-i*2pi*1024*s/NS}
    const float2 q2  = cmul(q1, q1);
    const float2 q3  = cmul(q2, q1);
    const float2 q4  = cmul(q2, q2);
    float2 phb = ph0;
#pragma unroll
    for (int t = 0; t < 8; ++t) {                  // k = 0..8191 (+ partners)
        int k = tid + (t << 10);
        float2 ph;
        switch (t & 3) {
            case 0:  ph = phb; break;
            case 1:  ph = cmul(phb, q1); break;
            case 2:  ph = cmul(phb, q2); break;
            default: ph = cmul(phb, q3); break;
        }
        if (k == 0) {
            // slot 0: Z'[0] = ((DC+Nq)/2, (DC-Nq)/2), Nq = X[M]*cos(pi*s)
            float2 z0 = lds[ldsIdx(0)];
            float X0 = z0.x + z0.y;
            float XM = z0.x - z0.y;
            float Nq = XM * phM.x;
            spec[0] = make_float2(0.5f * (X0 + Nq), 0.5f * (X0 - Nq));
            // self-paired slot M/2: X[M/2] = conj(Z[M/2]); Z'[M/2] = conj(A[M/2])
            float2 Zh = lds[ldsIdx(M / 2)];
            float2 Xh = make_float2(Zh.x, -Zh.y);
            float2 ph_h = shift_phase(M / 2, si, sf);
            float2 Ah = cmul(Xh, ph_h);
            spec[M / 2] = make_float2(Ah.x, -Ah.y);
        } else {
            float2 Zk = lds[ldsIdx(k)];
            float2 Zr = lds[ldsIdx(M - k)];
            float2 E = make_float2(0.5f * (Zk.x + Zr.x), 0.5f * (Zk.y - Zr.y));
            float2 O = make_float2(0.5f * (Zk.y + Zr.y), -0.5f * (Zk.x - Zr.x));
            float2 w = cmul(w0, make_float2(C32[t], -S32[t]));   // wNS(k)
            float2 wo = cmul(w, O);
            float2 Xk = make_float2(E.x + wo.x, E.y + wo.y);     // X[k]
            float2 Xm = make_float2(E.x - wo.x, wo.y - E.y);     // conj(E-wo)=X[M-k]
            float2 Ak = cmul(Xk, ph);
            float2 phm = cmul(phM, make_float2(ph.x, -ph.y));    // ph(M-k)
            float2 Am = cmul(Xm, phm);
            float2 z1, z2;
            zpair(Ak, Am, w, &z1, &z2);
            spec[k] = z1;
            spec[M - k] = z2;
        }
        if ((t & 3) == 3) phb = cmul(phb, q4);
    }
}

// Kernel B: pure elementwise sum of the 16 per-stem packed Z' rows per batch.
// Writes the batch's packed spectrum into d_out (8 MB, exactly out_size).
__global__ __launch_bounds__(256) void reduce_kernel(const float4* __restrict__ zbuf,
                                                     float4* __restrict__ out) {
    int gid = blockIdx.x * 256 + threadIdx.x;   // 0 .. NB*NS/4-1
    int b = gid >> 13;                           // / (NS/4)
    int i = gid & (NS / 4 - 1);
    const float4* base = zbuf + (size_t)b * NEV * (NS / 4) + i;
    float4 s = base[0];
#pragma unroll
    for (int e = 1; e < NEV; ++e) {
        float4 v = base[(size_t)e * (NS / 4)];
        s.x += v.x; s.y += v.y; s.z += v.z; s.w += v.w;
    }
    out[gid] = s;
}

// Kernel C: one block per batch. Z' is already packed & natural-order in
// d_out: fused load+stage0+scatter -> inverse stage pairs -> scaled real write.
__global__ __launch_bounds__(T2, 4) void inv_kernel(float* __restrict__ out) {
    __shared__ float2 lds[LDS_ELEMS];
    const int tid = threadIdx.x;
    const int b = blockIdx.x;
    float* rowp = out + (size_t)b * NS;

    load_stage0_scatter<1>((const float4*)rowp, lds, tid);
    __syncthreads();
    fft_pairs<1>(lds, tid);

    const float invM = 1.0f / (float)M;
    float4* dst = (float4*)rowp;
#pragma unroll
    for (int it = 0; it < (NS / 4) / T2; ++it) {
        int i = tid + it * T2;
        float2 z0 = lds[ldsIdx(2 * i)];
        float2 z1 = lds[ldsIdx(2 * i + 1)];
        dst[i] = make_float4(z0.x * invM, z0.y * invM, z1.x * invM, z1.y * invM);
    }
}

extern "C" void kernel_launch(void* const* d_in, const int* in_sizes, int n_in,
                              void* d_out, int out_size, void* d_ws, size_t ws_size,
                              hipStream_t stream) {
    const float* time_latent = (const float*)d_in[0];
    float* stems = (float*)d_in[1];
    // d_in[2] = targets: unused by the reference output
    const float* W_pos = (const float*)d_in[3];
    const float* b_pos = (const float*)d_in[4];
    float* out = (float*)d_out;

    // Use workspace for the per-stem Z' spectra when it's big enough —
    // leaves the stems input unclobbered (cheaper harness re-poison).
    const size_t ZBYTES = (size_t)NB * NEV * NS * sizeof(float);   // 128 MB
    float* zbuf = (ws_size >= ZBYTES) ? (float*)d_ws : stems;

    fft_phase_kernel<<<NB * NEV, T2, 0, stream>>>(stems, zbuf, time_latent,
                                                  W_pos, b_pos);
    reduce_kernel<<<(NB * NS / 4) / 256, 256, 0, stream>>>((const float4*)zbuf,
                                                           (float4*)out);
    inv_kernel<<<NB, T2, 0, stream>>>(out);
}